// Round 11
// baseline (176.592 us; speedup 1.0000x reference)
//
#include <hip/hip_runtime.h>
#include <cstdint>

// B=2, Q=512, K=512, T=256 (fp32 in/out).
// R18: R17 with the epilogue-slot fix (31%3 == 1, NOT 2 — R17 read the slot
// that iteration 31's reset had just zeroed -> inf/NaN).
// Structure: R16 (mfma 32x32x16, e^M identity) + apply(kk-1) pipelined to
// head of iteration kk (overlaps fragment ds_reads). Slots per iteration kk:
// head-apply reads (kk+2)%3 (==(kk-1)%3), atomics kk%3, reset (kk+1)%3,
// barrier. Epilogue applies kk=31 from slot 1.
// proj3/gemm_out exact R16.

typedef short bf16x8 __attribute__((ext_vector_type(8)));   // 8 bf16 = 4 VGPR
typedef float f32x4  __attribute__((ext_vector_type(4)));
typedef float f32x16 __attribute__((ext_vector_type(16)));  // 32x32 C/D frag

__device__ inline float bf2f(short s) {
  return __uint_as_float(((unsigned)(unsigned short)s) << 16);
}
// f32 pair -> packed bf16 (round-half-up), low short = lo
__device__ inline unsigned packrn(float lo, float hi) {
  return __builtin_amdgcn_perm(__float_as_uint(hi) + 0x8000u,
                               __float_as_uint(lo) + 0x8000u, 0x07060302u);
}

// GEMM body, 32x64 tile, 256 thr, prefetch-pipelined (exact R15/R16).
#define GEMM_BODY32(X, W, K0, K1)                                               \
  __shared__ __align__(16) float As[16][36];                                    \
  __shared__ __align__(16) float Ws[16][68];                                    \
  const int tid = threadIdx.x;                                                  \
  const int tx4 = (tid & 15) * 4;                                               \
  const int ty2 = (tid >> 4) * 2;                                               \
  const int m0 = blockIdx.x * 32, u0 = blockIdx.y * 64;                         \
  const int lmi = tid >> 2, lc4 = (tid & 3) * 4;                                \
  const bool hasA = tid < 128;                                                  \
  float4 xa, wb;                                                                \
  if (hasA) xa = *(const float4*)&(X)[(size_t)(m0 + lmi) * 256 + (K0) + lc4];   \
  wb = *(const float4*)&(W)[(size_t)(u0 + lmi) * 256 + (K0) + lc4];             \
  float c[2][4] = {};                                                           \
  _Pragma("unroll 1")                                                           \
  for (int t0 = (K0); t0 < (K1); t0 += 16) {                                    \
    __syncthreads();                                                            \
    if (hasA) {                                                                 \
      As[lc4 + 0][lmi] = xa.x; As[lc4 + 1][lmi] = xa.y;                         \
      As[lc4 + 2][lmi] = xa.z; As[lc4 + 3][lmi] = xa.w;                         \
    }                                                                           \
    Ws[lc4 + 0][lmi] = wb.x; Ws[lc4 + 1][lmi] = wb.y;                           \
    Ws[lc4 + 2][lmi] = wb.z; Ws[lc4 + 3][lmi] = wb.w;                           \
    __syncthreads();                                                            \
    if (t0 + 16 < (K1)) {                                                       \
      if (hasA) xa = *(const float4*)&(X)[(size_t)(m0 + lmi) * 256 + t0 + 16 + lc4]; \
      wb = *(const float4*)&(W)[(size_t)(u0 + lmi) * 256 + t0 + 16 + lc4];      \
    }                                                                           \
    _Pragma("unroll")                                                           \
    for (int t = 0; t < 16; ++t) {                                              \
      const float2 a = *(const float2*)&As[t][ty2];                             \
      const float4 w = *(const float4*)&Ws[t][tx4];                             \
      c[0][0] += a.x*w.x; c[0][1] += a.x*w.y; c[0][2] += a.x*w.z; c[0][3] += a.x*w.w; \
      c[1][0] += a.y*w.x; c[1][1] += a.y*w.y; c[1][2] += a.y*w.z; c[1][3] += a.y*w.w; \
    }                                                                           \
  }

// Projections + aux. z=0 key->kproj(f32), z=1 value->vproj(f32),
// z=2 query->qpF (bf16, 32x32 A-frag-major), z=3: WalF copy + vsum/out zero.
__global__ __launch_bounds__(256) void proj3(
    const float* __restrict__ key, const float* __restrict__ value,
    const float* __restrict__ query, const float* __restrict__ Wk,
    const float* __restrict__ Wq, const float* __restrict__ Wva,
    const float* __restrict__ Wal, float* __restrict__ kproj,
    float* __restrict__ vproj, short* __restrict__ qpF,
    short* __restrict__ WalF, float* __restrict__ vsum,
    float* __restrict__ outz)
{
  const int z = blockIdx.z;
  if (z == 3) {
    const int p = blockIdx.x * 4 + blockIdx.y;    // 0..127, use 0..63
    if (p >= 64) return;
    const int t256 = threadIdx.x;
    // WalF: plain row-major bf16 copy of Wal [u][t]
#pragma unroll
    for (int e = 0; e < 4; ++e) {
      const int d = p * 1024 + t256 * 4 + e;
      const float v = Wal[d];
      WalF[d] = (short)packrn(v, v);
    }
    // vsum + out zero: 4096 floats each per block
    float4* vz = (float4*)(vsum + p * 4096);
    float4* oz = (float4*)(outz + p * 4096);
#pragma unroll
    for (int e = 0; e < 4; ++e) {
      vz[t256 * 4 + e] = make_float4(0.f, 0.f, 0.f, 0.f);
      oz[t256 * 4 + e] = make_float4(0.f, 0.f, 0.f, 0.f);
    }
    return;
  }
  const float* X = (z == 0) ? key : (z == 1) ? value : query;
  const float* W = (z == 0) ? Wk  : (z == 1) ? Wva   : Wq;
  GEMM_BODY32(X, W, 0, 256);
  if (z == 2) {
    // 32x32x16 A-frag layout: element (q,t) -> g32=q>>5, row=q&31,
    // ts=t>>4, khalf=(t>>3)&1, j=t&7, lane=khalf*32+row.
    const int tbase = u0 + tx4;                   // t coordinate (4-aligned)
    const int ts = tbase >> 4, khalf = (tbase >> 3) & 1, j0 = tbase & 7;
#pragma unroll
    for (int i = 0; i < 2; ++i) {
      const int m = m0 + ty2 + i;                 // global row = b*512 + q
      const int bb = m >> 9, q = m & 511;
      const int g32 = q >> 5, row = q & 31;
      const int lane = khalf * 32 + row;
      const size_t idx =
          (((size_t)(bb * 16 + g32) * 16 + ts) * 64 + lane) * 8 + j0;
      uint2 s; s.x = packrn(c[i][0], c[i][1]); s.y = packrn(c[i][2], c[i][3]);
      *(uint2*)&qpF[idx] = s;
    }
  } else {
    float* C = (z == 0) ? kproj : vproj;
#pragma unroll
    for (int i = 0; i < 2; ++i)
      *(float4*)&C[(size_t)(m0 + ty2 + i) * 256 + u0 + tx4] =
          make_float4(c[i][0], c[i][1], c[i][2], c[i][3]);
  }
}

// Final projection: out += vsum x Wvo^T over K half blockIdx.z (split-K).
__global__ __launch_bounds__(256) void gemm_out(
    const float* __restrict__ X, const float* __restrict__ W, float* __restrict__ out)
{
  const int kh = blockIdx.z * 128;
  GEMM_BODY32(X, W, kh, kh + 128);
#pragma unroll
  for (int i = 0; i < 2; ++i)
#pragma unroll
    for (int j = 0; j < 4; ++j)
      atomicAdd(&out[(size_t)(m0 + ty2 + i) * 256 + u0 + tx4 + j], c[i][j]);
}

union Frag  { bf16x8 v; unsigned u[4]; };
union Acc16 { f32x16 v; f32x4 f4[4]; };

// ---------------------------------------------------------------------------
// kernelC: grid (16 kt, 8 uc, 2 b), 512 thr = 8 waves; wave w: q in
// [w*64, w*64+64) as 2x 32x32 MFMA tiles, full 32-u chunk. qa (128 VGPR)
// pinned. Per k (ONE barrier): apply(kk-1) at head (overlaps frag ds_reads);
// 32x MFMA 32x32x16 from W2F[k&1]; build W2F[(k+1)&1]; per-lane stats over
// own 32 q (e^M identity), 1 shfl_xor(32), lane<32 atomics (slot kk%3);
// reset slot (kk+1)%3; barrier. Epilogue applies kk=31 from slot 1 (31%3).
// lg/acc pinned to "v" class (no AGPR shuttling).
// ---------------------------------------------------------------------------
__global__ __launch_bounds__(512, 2) void kernelC(
    const short* __restrict__ qpF, const float* __restrict__ kproj,
    const float* __restrict__ vproj, const short* __restrict__ WalF,
    float* __restrict__ vsum)
{
  __shared__ __align__(16) short W2F[2][8192];  // [cs][(ts*64 + lane)*8]
  __shared__ float vpS[32 * 33];                // vproj tile [kk][u], padded
  __shared__ unsigned statM[96];                // 3 slots x 32 u (float bits of EM)
  __shared__ float statS[96];                   // 3 slots x 32 u

  const int kt = blockIdx.x, uc = blockIdx.y, b = blockIdx.z;
  const int u0 = uc * 32, k0 = kt * 32;
  const int tid = threadIdx.x;
  const int lane = tid & 63, w = tid >> 6;      // w in [0,8)
  const int ul = lane & 31;                     // u column (C: col=lane&31)
  const int tsb = tid >> 5, ub = tid & 31;      // build mapping: (ts, u)

  if (tid < 96) { statM[tid] = 0u; statS[tid] = 0.f; }
  {
    const int kk = tid >> 4, uu2 = (tid & 15) * 2;
    const float2 v2 = *(const float2*)&vproj[(size_t)(b * 512 + k0 + kk) * 256 + u0 + uu2];
    vpS[kk * 33 + uu2] = v2.x; vpS[kk * 33 + uu2 + 1] = v2.y;
  }

  // k-invariant Wal octets for (u=ub, t = tsb*16 + 0..15), f32-expanded
  float wl0[8], wl1[8];
  {
    const bf16x8 w0 = *(const bf16x8*)&WalF[(size_t)(uc * 32 + ub) * 256 + tsb * 16];
    const bf16x8 w1 = *(const bf16x8*)&WalF[(size_t)(uc * 32 + ub) * 256 + tsb * 16 + 8];
#pragma unroll
    for (int j = 0; j < 8; ++j) { wl0[j] = bf2f(w0[j]); wl1[j] = bf2f(w1[j]); }
  }

  // persistent A-fragments (2 q-tiles x 16 t-steps = 128 VGPR), pinned
  const short* qbase = qpF + (size_t)b * 131072;
  Frag qa[2][16];
#pragma unroll
  for (int qt = 0; qt < 2; ++qt)
#pragma unroll
    for (int ts = 0; ts < 16; ++ts) {
      qa[qt][ts].v = *(const bf16x8*)&qbase[(((size_t)(w * 2 + qt) * 16 + ts) * 64 + lane) * 8];
      asm volatile("" : "+v"(qa[qt][ts].u[0]), "+v"(qa[qt][ts].u[1]),
                        "+v"(qa[qt][ts].u[2]), "+v"(qa[qt][ts].u[3]));
    }

  // per-thread constant addresses
  const int fb = lane * 8;                                            // frag base
  const float* kq = &kproj[(long)(b * 512 + k0) * 256 + tsb * 16];    // kp base

  // prologue: build W2F[0] for k = k0 (two octets per thread)
  {
    const f32x4 a0 = *(const f32x4*)(kq);
    const f32x4 a1 = *(const f32x4*)(kq + 4);
    const f32x4 a2 = *(const f32x4*)(kq + 8);
    const f32x4 a3 = *(const f32x4*)(kq + 12);
    uint4 st;
    st.x = packrn(wl0[0] * a0[0], wl0[1] * a0[1]);
    st.y = packrn(wl0[2] * a0[2], wl0[3] * a0[3]);
    st.z = packrn(wl0[4] * a1[0], wl0[5] * a1[1]);
    st.w = packrn(wl0[6] * a1[2], wl0[7] * a1[3]);
    *(uint4*)&W2F[0][(tsb * 64 + ub) * 8] = st;
    st.x = packrn(wl1[0] * a2[0], wl1[1] * a2[1]);
    st.y = packrn(wl1[2] * a2[2], wl1[3] * a2[3]);
    st.z = packrn(wl1[4] * a3[0], wl1[5] * a3[1]);
    st.w = packrn(wl1[6] * a3[2], wl1[7] * a3[3]);
    *(uint4*)&W2F[0][(tsb * 64 + 32 + ub) * 8] = st;
  }
  __syncthreads();

  Acc16 acc[2];
  acc[0].v = 0.f; acc[1].v = 0.f;
  Acc16 lg[2];          // p-values of iteration kk-1 at loop head
  lg[0].v = 0.f; lg[1].v = 0.f;

#pragma unroll 1
  for (int kk = 0; kk < 32; ++kk) {
    const int cs = kk & 1, ss = kk % 3;

    // issue next k's kp loads early (hidden under MFMA)
    f32x4 a0, a1, a2, a3;
    if (kk < 31) {
      const float* kn = kq + (size_t)(kk + 1) * 256;
      a0 = *(const f32x4*)(kn);
      a1 = *(const f32x4*)(kn + 4);
      a2 = *(const f32x4*)(kn + 8);
      a3 = *(const f32x4*)(kn + 12);
    }

    // apply(kk-1) at head: stats finalized by barrier(kk-1); overlaps the
    // fragment ds_reads below. g = vp / (S + e^M) (rcp).
    if (kk > 0) {
      const int as = (kk + 2) % 3;               // == (kk-1)%3
      const float EMf = __uint_as_float(statM[as * 32 + ul]);
      const float Sf  = statS[as * 32 + ul];
      const float g = vpS[(kk - 1) * 33 + ul] * __builtin_amdgcn_rcpf(Sf + EMf);
#pragma unroll
      for (int qt = 0; qt < 2; ++qt)
#pragma unroll
        for (int r = 0; r < 16; ++r)
          acc[qt].f4[r >> 2][r & 3] =
              fmaf(g, lg[qt].f4[r >> 2][r & 3], acc[qt].f4[r >> 2][r & 3]);
      // pin accumulators into arch VGPRs (prevent AGPR shuttling)
#pragma unroll
      for (int qt = 0; qt < 2; ++qt)
        asm volatile("" : "+v"(acc[qt].f4[0]), "+v"(acc[qt].f4[1]),
                          "+v"(acc[qt].f4[2]), "+v"(acc[qt].f4[3]));
    }

    lg[0].v = 0.f; lg[1].v = 0.f;
#pragma unroll
    for (int ts = 0; ts < 16; ++ts) {
      const bf16x8 f = *(const bf16x8*)&W2F[cs][ts * 512 + fb];
      lg[0].v = __builtin_amdgcn_mfma_f32_32x32x16_bf16(qa[0][ts].v, f, lg[0].v, 0, 0, 0);
      lg[1].v = __builtin_amdgcn_mfma_f32_32x32x16_bf16(qa[1][ts].v, f, lg[1].v, 0, 0, 0);
    }

    // build next slot FIRST (independent of lg) so its VALU/ds_writes
    // co-issue under the MFMA shadow. (slot read last at kk-1, barrier between)
    if (kk < 31) {
      uint4 st;
      st.x = packrn(wl0[0] * a0[0], wl0[1] * a0[1]);
      st.y = packrn(wl0[2] * a0[2], wl0[3] * a0[3]);
      st.z = packrn(wl0[4] * a1[0], wl0[5] * a1[1]);
      st.w = packrn(wl0[6] * a1[2], wl0[7] * a1[3]);
      *(uint4*)&W2F[cs ^ 1][(tsb * 64 + ub) * 8] = st;
      st.x = packrn(wl1[0] * a2[0], wl1[1] * a2[1]);
      st.y = packrn(wl1[2] * a2[2], wl1[3] * a2[3]);
      st.z = packrn(wl1[4] * a3[0], wl1[5] * a3[1]);
      st.w = packrn(wl1[6] * a3[2], wl1[7] * a3[3]);
      *(uint4*)&W2F[cs ^ 1][(tsb * 64 + 32 + ub) * 8] = st;
    }

    // pin MFMA results into arch VGPRs (prevent AGPR residency -> shuttles)
#pragma unroll
    for (int qt = 0; qt < 2; ++qt)
      asm volatile("" : "+v"(lg[qt].f4[0]), "+v"(lg[qt].f4[1]),
                        "+v"(lg[qt].f4[2]), "+v"(lg[qt].f4[3]));

    // stats (e^M identity): e = exp(x), EM = max e, p = x*e, S = sum|p|.
    // Lane owns 32 q of ONE u column; partner lane^32 has the other 32 q
    // -> single shfl_xor(32) completes the in-block-per-wave reduce.
    float em[4] = {0.f, 0.f, 0.f, 0.f};
    float sp[4] = {0.f, 0.f, 0.f, 0.f};
#pragma unroll
    for (int qt = 0; qt < 2; ++qt)
#pragma unroll
      for (int r = 0; r < 16; ++r) {
        const float x = lg[qt].f4[r >> 2][r & 3];
        const float e = __expf(x);
        const float p = x * e;
        lg[qt].f4[r >> 2][r & 3] = p;
        em[r & 3] = fmaxf(em[r & 3], e);
        sp[r & 3] += fabsf(p);
      }
    float EM = fmaxf(fmaxf(em[0], em[1]), fmaxf(em[2], em[3]));
    float S  = (sp[0] + sp[1]) + (sp[2] + sp[3]);
    EM = fmaxf(EM, __shfl_xor(EM, 32));
    S += __shfl_xor(S, 32);
    if (lane < 32) {
      atomicMax(&statM[ss * 32 + ul], __float_as_uint(EM));  // EM>0: bits monotone
      atomicAdd(&statS[ss * 32 + ul], S);
    }
    // reset slot (kk+1)%3: last read (head-apply) at kk-1 pre-barrier(kk-1),
    // next atomiced at kk+1 post-barrier(kk) -> hazards barrier-separated.
    // Never equals ss (kk%3) or the head-apply slot ((kk+2)%3).
    const int rs = (kk + 1) % 3;
    if (tid < 32) { statM[rs * 32 + tid] = 0u; statS[rs * 32 + tid] = 0.f; }
    __syncthreads();
  }

  // epilogue apply for kk=31: slot 31%3 == 1 (NOT 2 — R17's bug; slot 2 was
  // just reset by iteration 31's rs=32%3==2).
  {
    const float EMf = __uint_as_float(statM[1 * 32 + ul]);
    const float Sf  = statS[1 * 32 + ul];
    const float g = vpS[31 * 33 + ul] * __builtin_amdgcn_rcpf(Sf + EMf);
#pragma unroll
    for (int qt = 0; qt < 2; ++qt)
#pragma unroll
      for (int r = 0; r < 16; ++r)
        acc[qt].f4[r >> 2][r & 3] =
            fmaf(g, lg[qt].f4[r >> 2][r & 3], acc[qt].f4[r >> 2][r & 3]);
  }

  // epilogue: C row = (r&3) + 8*(r>>2) + 4*(lane>>5), col = ul
#pragma unroll
  for (int qt = 0; qt < 2; ++qt)
#pragma unroll
    for (int r = 0; r < 16; ++r) {
      const int q = w * 64 + qt * 32 + (r & 3) + 8 * (r >> 2) + 4 * (lane >> 5);
      atomicAdd(&vsum[(size_t)(b * 512 + q) * 256 + u0 + ul],
                acc[qt].f4[r >> 2][r & 3]);
    }
}

extern "C" void kernel_launch(void* const* d_in, const int* in_sizes, int n_in,
                              void* d_out, int out_size, void* d_ws, size_t ws_size,
                              hipStream_t stream) {
  const float* query = (const float*)d_in[0];
  const float* key   = (const float*)d_in[1];
  const float* value = (const float*)d_in[2];
  const float* Wk    = (const float*)d_in[3];
  const float* Wq    = (const float*)d_in[4];
  const float* Wva   = (const float*)d_in[5];
  const float* Wal   = (const float*)d_in[6];
  const float* Wvo   = (const float*)d_in[7];
  float* ws = (float*)d_ws;

  float* kproj = ws;                        // 262144 f32
  float* vproj = kproj + 262144;
  float* vsum  = vproj + 262144;
  short* qpF   = (short*)(vsum + 262144);   // 262144 bf16, 32x32 A-frag-major
  short* WalF  = qpF + 262144;              // 65536 bf16, row-major copy
  float* out   = (float*)d_out;

  proj3<<<dim3(32, 4, 4), 256, 0, stream>>>(key, value, query, Wk, Wq, Wva, Wal,
                                            kproj, vproj, qpF, WalF, vsum, out);
  kernelC<<<dim3(16, 8, 2), 512, 0, stream>>>(qpF, kproj, vproj, WalF, vsum);
  gemm_out<<<dim3(32, 4, 2), 256, 0, stream>>>(vsum, Wvo, out);
}